// Round 4
// baseline (265.468 us; speedup 1.0000x reference)
//
#include <hip/hip_runtime.h>
#include <stdint.h>

// SynapticSNN — R11.
// R8-R10 post-mortem: absmax bit-identical (0.0859375) across THREE different
// MFMA split numerics (f16x2, f16x3, f16x3+prescale) -> flip set driven by
// the shared hi*hi fp32 accumulation-order noise (~1e-7), not split error.
// numpy's sgemm k-loop is a sequential fp32 FMA chain per output; the x67
// recurrence amplification + hard threshold turns ANY reordering (~1e-7) into
// ~100 deterministic spike flips (absmax ~ 4sigma of W2 ~ 0.086, matches).
// => GEMM1 MUST stay k-ascending sequential VALU FMA. MFMA-GEMM1 is
// structurally impossible, not a tuning failure.
// R11 changes: (a) k1 = round-0 form with BK 32->64 (bitwise-identical fmac
// chain, half the barriers); (b) k2 rebuilt LDS-free: grid (128,8)=1024
// blocks (4/CU vs 1/CU), MFMA fragments straight from global (spk/W2 are
// L2-resident), W2 converted fp32->bf16 in-register. k2 reordering is safe:
// spikes exact {0,1}, no recurrence downstream, err ~1e-6 << 0.068 threshold.
// k3 unchanged. R7 reminder: no fused atomic epilogue (256MB RMW disaster).

typedef __attribute__((ext_vector_type(8))) short short8;
typedef __attribute__((ext_vector_type(4))) float floatx4;

#define NSTEPS 100

static __device__ __forceinline__ uint32_t f2bf2(float lo, float hi) {
  union { float f; uint32_t u; } a, b; a.f = lo; b.f = hi;
  uint32_t x = (a.u + 0x7FFFu + ((a.u >> 16) & 1u)) >> 16;
  uint32_t y = (b.u + 0x7FFFu + ((b.u >> 16) & 1u)) & 0xFFFF0000u;
  return x | y;
}

// ---------------------------------------------------------------------------
// Kernel 1: GEMM1 64x64 tile 4x4/thread BK=64 + recurrence.
// Accumulation per output is k=0..255 ascending, one fmac per k — BITWISE
// identical to the passing round-0 kernel (BK only changes staging grouping).
// spk (bf16 {0,1}) [4096,2048] -> ws.
// ---------------------------------------------------------------------------
__global__ __launch_bounds__(256, 4) void snn_k1(
    const float* __restrict__ X, const float* __restrict__ W1,
    const float* __restrict__ b1, const float* __restrict__ betap,
    uint16_t* __restrict__ spk)
{
  __shared__ __align__(16) float As[64 * 68];   // [k][row+pad]
  __shared__ __align__(16) float Bs[64 * 68];
  const int tid = threadIdx.x;
  const int bm  = blockIdx.y * 64;   // batch rows
  const int bn  = blockIdx.x * 64;   // hidden cols
  const int ty  = tid >> 4;          // 0..15
  const int tx  = tid & 15;          // 0..15
  const int sc  = tid & 7;           // staging k-group (4 floats)
  const int sr  = tid >> 3;          // staging row 0..31

  float acc[4][4] = {};

  float4 xa[2][2], wa[2][2];         // [rowhalf][khalf]
  #pragma unroll
  for (int h = 0; h < 2; ++h) {
    const int r = sr + h * 32;
    #pragma unroll
    for (int kh = 0; kh < 2; ++kh) {
      xa[h][kh] = *(const float4*)(X  + (size_t)(bm + r) * 256 + kh * 32 + sc * 4);
      wa[h][kh] = *(const float4*)(W1 + (size_t)(bn + r) * 256 + kh * 32 + sc * 4);
    }
  }

  #pragma unroll 1
  for (int k0 = 0; k0 < 256; k0 += 64) {
    #pragma unroll
    for (int h = 0; h < 2; ++h) {
      const int r = sr + h * 32;
      #pragma unroll
      for (int kh = 0; kh < 2; ++kh) {
        const int kb = kh * 32 + sc * 4;
        As[(kb + 0) * 68 + r] = xa[h][kh].x;
        As[(kb + 1) * 68 + r] = xa[h][kh].y;
        As[(kb + 2) * 68 + r] = xa[h][kh].z;
        As[(kb + 3) * 68 + r] = xa[h][kh].w;
        Bs[(kb + 0) * 68 + r] = wa[h][kh].x;
        Bs[(kb + 1) * 68 + r] = wa[h][kh].y;
        Bs[(kb + 2) * 68 + r] = wa[h][kh].z;
        Bs[(kb + 3) * 68 + r] = wa[h][kh].w;
      }
    }
    __syncthreads();

    if (k0 < 192) {
      const int kn = k0 + 64;
      #pragma unroll
      for (int h = 0; h < 2; ++h) {
        const int r = sr + h * 32;
        #pragma unroll
        for (int kh = 0; kh < 2; ++kh) {
          xa[h][kh] = *(const float4*)(X  + (size_t)(bm + r) * 256 + kn + kh * 32 + sc * 4);
          wa[h][kh] = *(const float4*)(W1 + (size_t)(bn + r) * 256 + kn + kh * 32 + sc * 4);
        }
      }
    }

    #pragma unroll
    for (int kk = 0; kk < 64; ++kk) {
      const float4 a4 = *(const float4*)(As + kk * 68 + ty * 4);
      const float4 b4 = *(const float4*)(Bs + kk * 68 + tx * 4);
      const float av[4] = {a4.x, a4.y, a4.z, a4.w};
      const float bv[4] = {b4.x, b4.y, b4.z, b4.w};
      #pragma unroll
      for (int i = 0; i < 4; ++i)
        #pragma unroll
        for (int j = 0; j < 4; ++j)
          acc[i][j] += av[i] * bv[j];
    }
    __syncthreads();
  }

  float beta = betap[0];
  beta = fminf(fmaxf(beta, 0.0f), 1.0f);
  float bias[4];
  #pragma unroll
  for (int j = 0; j < 4; ++j) bias[j] = b1[bn + tx * 4 + j];

  float cc[16];
  #pragma unroll
  for (int i = 0; i < 4; ++i)
    #pragma unroll
    for (int j = 0; j < 4; ++j)
      cc[i * 4 + j] = acc[i][j] + bias[j];

  #pragma unroll
  for (int h = 0; h < 2; ++h) {
    float syn[8], mem[8];
    #pragma unroll
    for (int e = 0; e < 8; ++e) { syn[e] = 0.0f; mem[e] = 0.0f; }

    #pragma unroll 1
    for (int t = 0; t < NSTEPS; ++t) {
      #pragma unroll
      for (int e = 0; e < 8; ++e) {
        const float rst = (mem[e] > 1.0f) ? 1.0f : 0.0f;   // pre-update reset
        syn[e] = __fadd_rn(__fmul_rn(0.9f, syn[e]), cc[h * 8 + e]);
        mem[e] = __fsub_rn(__fadd_rn(__fmul_rn(beta, mem[e]), syn[e]), rst);
      }
    }

    #pragma unroll
    for (int i = 0; i < 2; ++i) {
      ushort4 o;
      o.x = (mem[i * 4 + 0] > 1.0f) ? (uint16_t)0x3F80u : (uint16_t)0u;
      o.y = (mem[i * 4 + 1] > 1.0f) ? (uint16_t)0x3F80u : (uint16_t)0u;
      o.z = (mem[i * 4 + 2] > 1.0f) ? (uint16_t)0x3F80u : (uint16_t)0u;
      o.w = (mem[i * 4 + 3] > 1.0f) ? (uint16_t)0x3F80u : (uint16_t)0u;
      *(ushort4*)(spk + (size_t)(bm + ty * 4 + h * 2 + i) * 2048 + bn + tx * 4) = o;
    }
  }
}

// ---------------------------------------------------------------------------
// Kernel 2 (R11): spk[4096,2048](bf16) @ W2[128,2048]^T, 16x16x32 bf16 MFMA,
// LDS-FREE. M-tile 32, N=128 full, split-K=8 -> grid (128,8) = 1024 blocks
// (4/CU). Fragments loaded straight from global: spk chunk (128 KB/block,
// shared by all 4 waves) and W2 (1 MB) are L2-resident. W2 fp32->bf16 (rne)
// in-register. part[kc][4096][128] fp32 -> ws.
// Fragment layout (verified m89/m91): A/B [m=lane&15][k=(lane>>4)*8+j];
// C/D col=lane&15, row=(lane>>4)*4+reg.
// ---------------------------------------------------------------------------
__global__ __launch_bounds__(256) void snn_k2(
    const uint16_t* __restrict__ spk, const float* __restrict__ W2,
    float* __restrict__ part)
{
  const int tid  = threadIdx.x;
  const int lane = tid & 63;
  const int w    = tid >> 6;        // 4 waves
  const int wn   = w * 32;          // wave n-offset: 4 x 32 = 128
  const int bm   = blockIdx.x * 32; // 128 m-blocks
  const int kc   = blockIdx.y;      // K chunk of 256
  const int fe   = lane & 15;
  const int kq   = lane >> 4;

  floatx4 acc[2][2] = {};

  const uint16_t* a0 = spk + (size_t)(bm + fe) * 2048 + kc * 256 + kq * 8;
  const uint16_t* a1 = a0 + (size_t)16 * 2048;
  const float* b0 = W2 + (size_t)(wn + fe) * 2048 + kc * 256 + kq * 8;
  const float* b1p = b0 + (size_t)16 * 2048;

  #pragma unroll
  for (int kb = 0; kb < 8; ++kb) {
    const int ko = kb * 32;
    short8 a8[2], b8[2];
    a8[0] = *(const short8*)(a0 + ko);
    a8[1] = *(const short8*)(a1 + ko);
    #pragma unroll
    for (int tn = 0; tn < 2; ++tn) {
      const float* wp = (tn == 0) ? (b0 + ko) : (b1p + ko);
      const float4 w0 = *(const float4*)(wp);
      const float4 w1 = *(const float4*)(wp + 4);
      union { int4 i4; short8 s8; } pk;
      pk.i4.x = (int)f2bf2(w0.x, w0.y);
      pk.i4.y = (int)f2bf2(w0.z, w0.w);
      pk.i4.z = (int)f2bf2(w1.x, w1.y);
      pk.i4.w = (int)f2bf2(w1.z, w1.w);
      b8[tn] = pk.s8;
    }
    #pragma unroll
    for (int tm = 0; tm < 2; ++tm)
      #pragma unroll
      for (int tn = 0; tn < 2; ++tn)
        acc[tm][tn] = __builtin_amdgcn_mfma_f32_16x16x32_bf16(
            a8[tm], b8[tn], acc[tm][tn], 0, 0, 0);
  }

  #pragma unroll
  for (int tm = 0; tm < 2; ++tm)
    #pragma unroll
    for (int tn = 0; tn < 2; ++tn)
      #pragma unroll
      for (int r = 0; r < 4; ++r) {
        const int row = bm + tm * 16 + kq * 4 + r;
        const int col = wn + tn * 16 + fe;
        part[((size_t)kc * 4096 + row) * 128 + col] = acc[tm][tn][r];
      }
}

// ---------------------------------------------------------------------------
// Kernel 3 (unchanged): out[m][n] = sum_kc part[kc][m][n] + b2[n]  (fp32 out)
// ---------------------------------------------------------------------------
__global__ __launch_bounds__(256) void snn_k3(
    const float* __restrict__ part, const float* __restrict__ b2,
    float* __restrict__ out)
{
  const int idx = blockIdx.x * 256 + threadIdx.x;
  const int m = idx >> 5;
  const int c = (idx & 31) << 2;
  float s0 = 0.f, s1 = 0.f, s2 = 0.f, s3 = 0.f;
  #pragma unroll
  for (int kc = 0; kc < 8; ++kc) {
    const float4 p = *(const float4*)(part + ((size_t)kc * 4096 + m) * 128 + c);
    s0 += p.x; s1 += p.y; s2 += p.z; s3 += p.w;
  }
  float4 o;
  o.x = s0 + b2[c + 0];
  o.y = s1 + b2[c + 1];
  o.z = s2 + b2[c + 2];
  o.w = s3 + b2[c + 3];
  *(float4*)(out + (size_t)m * 128 + c) = o;
}

extern "C" void kernel_launch(void* const* d_in, const int* in_sizes, int n_in,
                              void* d_out, int out_size, void* d_ws, size_t ws_size,
                              hipStream_t stream) {
  const float* X    = (const float*)d_in[0];  // [4096,256]
  const float* W1   = (const float*)d_in[1];  // [2048,256]
  const float* b1   = (const float*)d_in[2];  // [2048]
  const float* W2   = (const float*)d_in[3];  // [128,2048]
  const float* b2   = (const float*)d_in[4];  // [128]
  const float* beta = (const float*)d_in[5];  // scalar
  float* out = (float*)d_out;                 // [4096,128] fp32

  uint16_t* spk = (uint16_t*)d_ws;                               // 16 MiB
  float* part = (float*)((char*)d_ws + (size_t)4096 * 2048 * 2); // 16 MiB

  snn_k1<<<dim3(32, 64), 256, 0, stream>>>(X, W1, b1, beta, spk);
  snn_k2<<<dim3(128, 8), 256, 0, stream>>>(spk, W2, part);
  snn_k3<<<512, 256, 0, stream>>>(part, b2, out);
}

// Round 6
// 236.192 us; speedup vs baseline: 1.1240x; 1.1240x over previous
//
#include <hip/hip_runtime.h>
#include <stdint.h>

// SynapticSNN — R12 (resubmit; R5 bench was an infra failure, no signal).
// R11 post-mortem: BK=64's doubled prefetch arrays spilled to scratch ->
// 394 MB HBM RMW traffic, k1 158->207us. Reverted.
// R8-R10 established: GEMM1 must keep k-ascending sequential fp32 fmac per
// output (any reorder -> ~1e-7 cur1 noise -> x67 recurrence amplification ->
// ~100 spike flips -> absmax 0.086 > 0.068). MFMA-GEMM1 impossible.
// R12 theory: fused k1 couples two conflicting shapes. GEMM phase is
// LDS-instruction-bound at 4x4/thread (2 ds_read_b128 per 16 fmac) because
// the fused recurrence state forbids bigger tiles; recurrence inherits 43%
// occupancy + barriers. Split: (a) snn_gemm1 128x128 tile 8x8/thread (64
// fmac per 4 ds_read_b128), per 1024-col half so cur1-half (16MB) fits the
// 'part' ws region; (b) snn_rec elementwise, 2048 blocks, ~95% VALU.
// Numerics bit-identical: cur1 stored/reloaded exact fp32; same k-order;
// same __f*_rn recurrence ops. k2/k3 = exact R0 proven versions.

typedef __attribute__((ext_vector_type(8))) short short8;
typedef __attribute__((ext_vector_type(4))) float floatx4;

#define NSTEPS 100

static __device__ __forceinline__ uint32_t f2bf2(float lo, float hi) {
  union { float f; uint32_t u; } a, b; a.f = lo; b.f = hi;
  uint32_t x = (a.u + 0x7FFFu + ((a.u >> 16) & 1u)) >> 16;
  uint32_t y = (b.u + 0x7FFFu + ((b.u >> 16) & 1u)) & 0xFFFF0000u;
  return x | y;
}

// ---------------------------------------------------------------------------
// Kernel 1a: GEMM-only. cur1h[4096,1024] = X @ W1h^T + b1h for one 1024-col
// half. 128x128 tile, 8x8/thread, BK=32, register-prefetch double buffer.
// Per-output accumulation: k0 ascending, kk ascending, single acc — BITWISE
// identical chain to the round-0 passing kernel. Grid (8, 32) = 256 blocks.
// ---------------------------------------------------------------------------
__global__ __launch_bounds__(256) void snn_gemm1(
    const float* __restrict__ X, const float* __restrict__ W1h,
    const float* __restrict__ b1h, float* __restrict__ cur1h)
{
  __shared__ __align__(16) float As[32 * 132];   // [k][row+pad]
  __shared__ __align__(16) float Bs[32 * 132];
  const int tid = threadIdx.x;
  const int bn  = blockIdx.x * 128;  // cols within half (0..896)
  const int bm  = blockIdx.y * 128;  // batch rows
  const int ty  = tid >> 4;          // 0..15 -> rows ty*8
  const int tx  = tid & 15;          // 0..15 -> cols tx*8
  const int sr  = tid >> 3;          // staging row 0..31
  const int sc  = tid & 7;           // staging k-group (4 floats)

  float acc[8][8] = {};

  float4 xa[4], wa[4];
  #pragma unroll
  for (int h = 0; h < 4; ++h) {
    const int r = h * 32 + sr;
    xa[h] = *(const float4*)(X   + (size_t)(bm + r) * 256 + sc * 4);
    wa[h] = *(const float4*)(W1h + (size_t)(bn + r) * 256 + sc * 4);
  }

  #pragma unroll 1
  for (int k0 = 0; k0 < 256; k0 += 32) {
    #pragma unroll
    for (int h = 0; h < 4; ++h) {
      const int r = h * 32 + sr;
      As[(sc * 4 + 0) * 132 + r] = xa[h].x;
      As[(sc * 4 + 1) * 132 + r] = xa[h].y;
      As[(sc * 4 + 2) * 132 + r] = xa[h].z;
      As[(sc * 4 + 3) * 132 + r] = xa[h].w;
      Bs[(sc * 4 + 0) * 132 + r] = wa[h].x;
      Bs[(sc * 4 + 1) * 132 + r] = wa[h].y;
      Bs[(sc * 4 + 2) * 132 + r] = wa[h].z;
      Bs[(sc * 4 + 3) * 132 + r] = wa[h].w;
    }
    __syncthreads();

    if (k0 < 224) {
      const int kn = k0 + 32;
      #pragma unroll
      for (int h = 0; h < 4; ++h) {
        const int r = h * 32 + sr;
        xa[h] = *(const float4*)(X   + (size_t)(bm + r) * 256 + kn + sc * 4);
        wa[h] = *(const float4*)(W1h + (size_t)(bn + r) * 256 + kn + sc * 4);
      }
    }

    #pragma unroll
    for (int kk = 0; kk < 32; ++kk) {
      const float4 a0 = *(const float4*)(As + kk * 132 + ty * 8);
      const float4 a1 = *(const float4*)(As + kk * 132 + ty * 8 + 4);
      const float4 b0 = *(const float4*)(Bs + kk * 132 + tx * 8);
      const float4 b1 = *(const float4*)(Bs + kk * 132 + tx * 8 + 4);
      const float av[8] = {a0.x, a0.y, a0.z, a0.w, a1.x, a1.y, a1.z, a1.w};
      const float bv[8] = {b0.x, b0.y, b0.z, b0.w, b1.x, b1.y, b1.z, b1.w};
      #pragma unroll
      for (int i = 0; i < 8; ++i)
        #pragma unroll
        for (int j = 0; j < 8; ++j)
          acc[i][j] += av[i] * bv[j];
    }
    __syncthreads();
  }

  float bias[8];
  #pragma unroll
  for (int j = 0; j < 8; ++j) bias[j] = b1h[bn + tx * 8 + j];

  #pragma unroll
  for (int i = 0; i < 8; ++i) {
    const int row = bm + ty * 8 + i;
    float4 o0, o1;
    o0.x = acc[i][0] + bias[0];
    o0.y = acc[i][1] + bias[1];
    o0.z = acc[i][2] + bias[2];
    o0.w = acc[i][3] + bias[3];
    o1.x = acc[i][4] + bias[4];
    o1.y = acc[i][5] + bias[5];
    o1.z = acc[i][6] + bias[6];
    o1.w = acc[i][7] + bias[7];
    *(float4*)(cur1h + (size_t)row * 1024 + bn + tx * 8)     = o0;
    *(float4*)(cur1h + (size_t)row * 1024 + bn + tx * 8 + 4) = o1;
  }
}

// ---------------------------------------------------------------------------
// Kernel 1b: recurrence-only. Reads cur1h[4096,1024] fp32, runs the exact
// 100-step recurrence in registers, writes spk (bf16 {0,1}) at col offset
// nh0. 8 elems/thread; grid 2048 blocks (8/CU) — zero LDS, zero barriers.
// ---------------------------------------------------------------------------
__global__ __launch_bounds__(256) void snn_rec(
    const float* __restrict__ cur1h, const float* __restrict__ betap,
    uint16_t* __restrict__ spk, int nh0)
{
  const int idx = blockIdx.x * 256 + threadIdx.x;   // 524288 threads
  const int row = idx >> 7;                          // 128 groups of 8 per row
  const int col = (idx & 127) * 8;

  const float4 c0 = *(const float4*)(cur1h + (size_t)row * 1024 + col);
  const float4 c1 = *(const float4*)(cur1h + (size_t)row * 1024 + col + 4);
  const float cc[8] = {c0.x, c0.y, c0.z, c0.w, c1.x, c1.y, c1.z, c1.w};

  float beta = betap[0];
  beta = fminf(fmaxf(beta, 0.0f), 1.0f);

  float syn[8], mem[8];
  #pragma unroll
  for (int e = 0; e < 8; ++e) { syn[e] = 0.0f; mem[e] = 0.0f; }

  // Exact reference op order: reset from pre-update mem; no FMA contraction.
  #pragma unroll 1
  for (int t = 0; t < NSTEPS; ++t) {
    #pragma unroll
    for (int e = 0; e < 8; ++e) {
      const float rst = (mem[e] > 1.0f) ? 1.0f : 0.0f;
      syn[e] = __fadd_rn(__fmul_rn(0.9f, syn[e]), cc[e]);
      mem[e] = __fsub_rn(__fadd_rn(__fmul_rn(beta, mem[e]), syn[e]), rst);
    }
  }

  ushort4 o0, o1;
  o0.x = (mem[0] > 1.0f) ? (uint16_t)0x3F80u : (uint16_t)0u;
  o0.y = (mem[1] > 1.0f) ? (uint16_t)0x3F80u : (uint16_t)0u;
  o0.z = (mem[2] > 1.0f) ? (uint16_t)0x3F80u : (uint16_t)0u;
  o0.w = (mem[3] > 1.0f) ? (uint16_t)0x3F80u : (uint16_t)0u;
  o1.x = (mem[4] > 1.0f) ? (uint16_t)0x3F80u : (uint16_t)0u;
  o1.y = (mem[5] > 1.0f) ? (uint16_t)0x3F80u : (uint16_t)0u;
  o1.z = (mem[6] > 1.0f) ? (uint16_t)0x3F80u : (uint16_t)0u;
  o1.w = (mem[7] > 1.0f) ? (uint16_t)0x3F80u : (uint16_t)0u;
  uint16_t* sp = spk + (size_t)row * 2048 + nh0 + col;
  *(ushort4*)(sp)     = o0;
  *(ushort4*)(sp + 4) = o1;
}

// ---------------------------------------------------------------------------
// Kernel 2 (R0 proven): spk[4096,2048](bf16) @ W2[128,2048]^T via 16x16x32
// bf16 MFMA. 128m x 128n tiles, split-K=8. part[kc][4096][128] fp32 -> ws.
// ---------------------------------------------------------------------------
#define PS 72

__global__ __launch_bounds__(256) void snn_k2(
    const uint16_t* __restrict__ spk, const float* __restrict__ W2,
    float* __restrict__ part)
{
  __shared__ short As[128 * PS];
  __shared__ short Bs[128 * PS];
  const int tid  = threadIdx.x;
  const int lane = tid & 63;
  const int w    = tid >> 6;
  const int wm   = (w >> 1) * 64;
  const int wn   = (w & 1) * 64;
  const int bm   = blockIdx.x * 128;
  const int kc   = blockIdx.y;          // K chunk of 256

  floatx4 acc[4][4] = {};

  #pragma unroll 1
  for (int kk = 0; kk < 4; ++kk) {
    const int k0 = kc * 256 + kk * 64;
    #pragma unroll
    for (int p = 0; p < 4; ++p) {
      const int u = p * 256 + tid;
      const int r = u >> 3, c = u & 7;
      const int4 va = *(const int4*)(spk + (size_t)(bm + r) * 2048 + k0 + c * 8);
      *(int4*)(As + r * PS + c * 8) = va;
    }
    #pragma unroll
    for (int p = 0; p < 4; ++p) {
      const int u = p * 256 + tid;
      const int n = u >> 3, c = u & 7;
      const float* wp = W2 + (size_t)n * 2048 + k0 + c * 8;
      const float4 w0 = *(const float4*)(wp);
      const float4 w1 = *(const float4*)(wp + 4);
      int4 pk;
      pk.x = (int)f2bf2(w0.x, w0.y);
      pk.y = (int)f2bf2(w0.z, w0.w);
      pk.z = (int)f2bf2(w1.x, w1.y);
      pk.w = (int)f2bf2(w1.z, w1.w);
      *(int4*)(Bs + n * PS + c * 8) = pk;
    }
    __syncthreads();

    #pragma unroll
    for (int ks = 0; ks < 2; ++ks) {
      const int kb = ks * 4 + (lane >> 4);
      const int fe = lane & 15;
      short8 a8[4], b8[4];
      #pragma unroll
      for (int tm = 0; tm < 4; ++tm)
        a8[tm] = *(const short8*)(As + (wm + tm * 16 + fe) * PS + kb * 8);
      #pragma unroll
      for (int tn = 0; tn < 4; ++tn)
        b8[tn] = *(const short8*)(Bs + (wn + tn * 16 + fe) * PS + kb * 8);
      #pragma unroll
      for (int tm = 0; tm < 4; ++tm)
        #pragma unroll
        for (int tn = 0; tn < 4; ++tn)
          acc[tm][tn] = __builtin_amdgcn_mfma_f32_16x16x32_bf16(
              a8[tm], b8[tn], acc[tm][tn], 0, 0, 0);
    }
    __syncthreads();
  }

  const int fe = lane & 15;
  const int fr = (lane >> 4) * 4;
  #pragma unroll
  for (int tm = 0; tm < 4; ++tm)
    #pragma unroll
    for (int tn = 0; tn < 4; ++tn)
      #pragma unroll
      for (int r = 0; r < 4; ++r) {
        const int row = bm + wm + tm * 16 + fr + r;
        const int col = wn + tn * 16 + fe;
        part[((size_t)kc * 4096 + row) * 128 + col] = acc[tm][tn][r];
      }
}

// ---------------------------------------------------------------------------
// Kernel 3 (R0 proven): out[m][n] = sum_kc part[kc][m][n] + b2[n]
// ---------------------------------------------------------------------------
__global__ __launch_bounds__(256) void snn_k3(
    const float* __restrict__ part, const float* __restrict__ b2,
    float* __restrict__ out)
{
  const int idx = blockIdx.x * 256 + threadIdx.x;
  const int m = idx >> 5;
  const int c = (idx & 31) << 2;
  float s0 = 0.f, s1 = 0.f, s2 = 0.f, s3 = 0.f;
  #pragma unroll
  for (int kc = 0; kc < 8; ++kc) {
    const float4 p = *(const float4*)(part + ((size_t)kc * 4096 + m) * 128 + c);
    s0 += p.x; s1 += p.y; s2 += p.z; s3 += p.w;
  }
  float4 o;
  o.x = s0 + b2[c + 0];
  o.y = s1 + b2[c + 1];
  o.z = s2 + b2[c + 2];
  o.w = s3 + b2[c + 3];
  *(float4*)(out + (size_t)m * 128 + c) = o;
}

extern "C" void kernel_launch(void* const* d_in, const int* in_sizes, int n_in,
                              void* d_out, int out_size, void* d_ws, size_t ws_size,
                              hipStream_t stream) {
  const float* X    = (const float*)d_in[0];  // [4096,256]
  const float* W1   = (const float*)d_in[1];  // [2048,256]
  const float* b1   = (const float*)d_in[2];  // [2048]
  const float* W2   = (const float*)d_in[3];  // [128,2048]
  const float* b2   = (const float*)d_in[4];  // [128]
  const float* beta = (const float*)d_in[5];  // scalar
  float* out = (float*)d_out;                 // [4096,128] fp32

  uint16_t* spk = (uint16_t*)d_ws;                                // 16 MiB
  float* part   = (float*)((char*)d_ws + (size_t)4096 * 2048 * 2); // 16 MiB
  // cur1 half [4096,1024] fp32 (16 MiB) aliases 'part' (dead until k2):
  float* cur1h = part;

  // half 0: hidden cols 0..1023
  snn_gemm1<<<dim3(8, 32), 256, 0, stream>>>(X, W1, b1, cur1h);
  snn_rec<<<2048, 256, 0, stream>>>(cur1h, beta, spk, 0);
  // half 1: hidden cols 1024..2047
  snn_gemm1<<<dim3(8, 32), 256, 0, stream>>>(
      X, W1 + (size_t)1024 * 256, b1 + 1024, cur1h);
  snn_rec<<<2048, 256, 0, stream>>>(cur1h, beta, spk, 1024);

  snn_k2<<<dim3(32, 8), 256, 0, stream>>>(spk, W2, part);
  snn_k3<<<512, 256, 0, stream>>>(part, b2, out);
}

// Round 8
// 226.150 us; speedup vs baseline: 1.1739x; 1.0444x over previous
//
#include <hip/hip_runtime.h>
#include <stdint.h>

// SynapticSNN — R14: single-delta round. R12 source (passed, 236us, absmax
// 0.015625) with ONLY snn_gemm1 swapped: 128Mx64N tile, 8x4/thread, grid
// (16,32)=512 blocks (2/CU vs R12's 1/CU).
// R13 post-mortem: failed 0.0859375 — same value as R8-R10 MFMA failures,
// though the change sets are disjoint. Conclusion: 0.0859375 is the GENERIC
// signature of any >=1-ulp deviation anywhere in cur1->recurrence (fixed
// near-threshold flip set + dominant W2 column). v_pk_*_f32 rec is BANNED
// (DP-datapath packed f32 is not bitwise == scalar VALU in some corner),
// as is MFMA GEMM1 (R8-R10). R13 bundled pk-rec + gemm-tile; this round
// isolates the gemm tile change, which preserves the k-ascending fmac chain
// per output bitwise (same += pattern that passed at 4x4 R0 / 8x8 R12).
// rec stays scalar __f*_rn (proven, at its 7-op issue floor, 49.9us/half).
// k2/k3 = R0 proven. R11 reminder: no fat prefetch arrays (scratch spills).

typedef __attribute__((ext_vector_type(8))) short short8;
typedef __attribute__((ext_vector_type(4))) float floatx4;

#define NSTEPS 100

static __device__ __forceinline__ uint32_t f2bf2(float lo, float hi) {
  union { float f; uint32_t u; } a, b; a.f = lo; b.f = hi;
  uint32_t x = (a.u + 0x7FFFu + ((a.u >> 16) & 1u)) >> 16;
  uint32_t y = (b.u + 0x7FFFu + ((b.u >> 16) & 1u)) & 0xFFFF0000u;
  return x | y;
}

// ---------------------------------------------------------------------------
// Kernel 1a: GEMM-only. cur1h[4096,1024] = X @ W1h^T + b1h for one 1024-col
// half. Tile 128M x 64N, 8x4/thread, BK=32, register-prefetch double buffer.
// Grid (16,32) = 512 blocks (2/CU). Per-output accumulation: k ascending,
// single fmac chain — bitwise identical to the round-0 passing kernel.
// ---------------------------------------------------------------------------
__global__ __launch_bounds__(256) void snn_gemm1(
    const float* __restrict__ X, const float* __restrict__ W1h,
    const float* __restrict__ b1h, float* __restrict__ cur1h)
{
  __shared__ __align__(16) float As[32 * 132];   // [k][m 128+pad]
  __shared__ __align__(16) float Bs[32 * 68];    // [k][n 64+pad]
  const int tid = threadIdx.x;
  const int bn  = blockIdx.x * 64;   // cols within half
  const int bm  = blockIdx.y * 128;  // batch rows
  const int ty  = tid >> 4;          // 0..15 -> rows ty*8
  const int tx  = tid & 15;          // 0..15 -> cols tx*4
  const int sr  = tid >> 3;          // staging row 0..31
  const int sc  = tid & 7;           // staging k-group (4 floats)

  float acc[8][4] = {};

  float4 xa[4], wa[2];
  #pragma unroll
  for (int h = 0; h < 4; ++h)
    xa[h] = *(const float4*)(X + (size_t)(bm + h * 32 + sr) * 256 + sc * 4);
  #pragma unroll
  for (int h = 0; h < 2; ++h)
    wa[h] = *(const float4*)(W1h + (size_t)(bn + h * 32 + sr) * 256 + sc * 4);

  #pragma unroll 1
  for (int k0 = 0; k0 < 256; k0 += 32) {
    #pragma unroll
    for (int h = 0; h < 4; ++h) {
      const int r = h * 32 + sr;
      As[(sc * 4 + 0) * 132 + r] = xa[h].x;
      As[(sc * 4 + 1) * 132 + r] = xa[h].y;
      As[(sc * 4 + 2) * 132 + r] = xa[h].z;
      As[(sc * 4 + 3) * 132 + r] = xa[h].w;
    }
    #pragma unroll
    for (int h = 0; h < 2; ++h) {
      const int r = h * 32 + sr;
      Bs[(sc * 4 + 0) * 68 + r] = wa[h].x;
      Bs[(sc * 4 + 1) * 68 + r] = wa[h].y;
      Bs[(sc * 4 + 2) * 68 + r] = wa[h].z;
      Bs[(sc * 4 + 3) * 68 + r] = wa[h].w;
    }
    __syncthreads();

    if (k0 < 224) {
      const int kn = k0 + 32;
      #pragma unroll
      for (int h = 0; h < 4; ++h)
        xa[h] = *(const float4*)(X + (size_t)(bm + h * 32 + sr) * 256 + kn + sc * 4);
      #pragma unroll
      for (int h = 0; h < 2; ++h)
        wa[h] = *(const float4*)(W1h + (size_t)(bn + h * 32 + sr) * 256 + kn + sc * 4);
    }

    #pragma unroll
    for (int kk = 0; kk < 32; ++kk) {
      const float4 a0 = *(const float4*)(As + kk * 132 + ty * 8);
      const float4 a1 = *(const float4*)(As + kk * 132 + ty * 8 + 4);
      const float4 b0 = *(const float4*)(Bs + kk * 68 + tx * 4);
      const float av[8] = {a0.x, a0.y, a0.z, a0.w, a1.x, a1.y, a1.z, a1.w};
      const float bv[4] = {b0.x, b0.y, b0.z, b0.w};
      #pragma unroll
      for (int i = 0; i < 8; ++i)
        #pragma unroll
        for (int j = 0; j < 4; ++j)
          acc[i][j] += av[i] * bv[j];
    }
    __syncthreads();
  }

  float bias[4];
  #pragma unroll
  for (int j = 0; j < 4; ++j) bias[j] = b1h[bn + tx * 4 + j];

  #pragma unroll
  for (int i = 0; i < 8; ++i) {
    const int row = bm + ty * 8 + i;
    float4 o;
    o.x = acc[i][0] + bias[0];
    o.y = acc[i][1] + bias[1];
    o.z = acc[i][2] + bias[2];
    o.w = acc[i][3] + bias[3];
    *(float4*)(cur1h + (size_t)row * 1024 + bn + tx * 4) = o;
  }
}

// ---------------------------------------------------------------------------
// Kernel 1b (R12 proven, unchanged): recurrence-only, scalar __f*_rn.
// Reads cur1h[4096,1024] fp32, exact 100-step recurrence in registers,
// writes spk (bf16 {0,1}) at col offset nh0. 8 elems/thread; 2048 blocks.
// ---------------------------------------------------------------------------
__global__ __launch_bounds__(256) void snn_rec(
    const float* __restrict__ cur1h, const float* __restrict__ betap,
    uint16_t* __restrict__ spk, int nh0)
{
  const int idx = blockIdx.x * 256 + threadIdx.x;   // 524288 threads
  const int row = idx >> 7;
  const int col = (idx & 127) * 8;

  const float4 c0 = *(const float4*)(cur1h + (size_t)row * 1024 + col);
  const float4 c1 = *(const float4*)(cur1h + (size_t)row * 1024 + col + 4);
  const float cc[8] = {c0.x, c0.y, c0.z, c0.w, c1.x, c1.y, c1.z, c1.w};

  float beta = betap[0];
  beta = fminf(fmaxf(beta, 0.0f), 1.0f);

  float syn[8], mem[8];
  #pragma unroll
  for (int e = 0; e < 8; ++e) { syn[e] = 0.0f; mem[e] = 0.0f; }

  // Exact reference op order: reset from pre-update mem; no FMA contraction.
  #pragma unroll 1
  for (int t = 0; t < NSTEPS; ++t) {
    #pragma unroll
    for (int e = 0; e < 8; ++e) {
      const float rst = (mem[e] > 1.0f) ? 1.0f : 0.0f;
      syn[e] = __fadd_rn(__fmul_rn(0.9f, syn[e]), cc[e]);
      mem[e] = __fsub_rn(__fadd_rn(__fmul_rn(beta, mem[e]), syn[e]), rst);
    }
  }

  ushort4 o0, o1;
  o0.x = (mem[0] > 1.0f) ? (uint16_t)0x3F80u : (uint16_t)0u;
  o0.y = (mem[1] > 1.0f) ? (uint16_t)0x3F80u : (uint16_t)0u;
  o0.z = (mem[2] > 1.0f) ? (uint16_t)0x3F80u : (uint16_t)0u;
  o0.w = (mem[3] > 1.0f) ? (uint16_t)0x3F80u : (uint16_t)0u;
  o1.x = (mem[4] > 1.0f) ? (uint16_t)0x3F80u : (uint16_t)0u;
  o1.y = (mem[5] > 1.0f) ? (uint16_t)0x3F80u : (uint16_t)0u;
  o1.z = (mem[6] > 1.0f) ? (uint16_t)0x3F80u : (uint16_t)0u;
  o1.w = (mem[7] > 1.0f) ? (uint16_t)0x3F80u : (uint16_t)0u;
  uint16_t* sp = spk + (size_t)row * 2048 + nh0 + col;
  *(ushort4*)(sp)     = o0;
  *(ushort4*)(sp + 4) = o1;
}

// ---------------------------------------------------------------------------
// Kernel 2 (R0 proven): spk[4096,2048](bf16) @ W2[128,2048]^T via 16x16x32
// bf16 MFMA. 128m x 128n tiles, split-K=8. part[kc][4096][128] fp32 -> ws.
// ---------------------------------------------------------------------------
#define PS 72

__global__ __launch_bounds__(256) void snn_k2(
    const uint16_t* __restrict__ spk, const float* __restrict__ W2,
    float* __restrict__ part)
{
  __shared__ short As[128 * PS];
  __shared__ short Bs[128 * PS];
  const int tid  = threadIdx.x;
  const int lane = tid & 63;
  const int w    = tid >> 6;
  const int wm   = (w >> 1) * 64;
  const int wn   = (w & 1) * 64;
  const int bm   = blockIdx.x * 128;
  const int kc   = blockIdx.y;          // K chunk of 256

  floatx4 acc[4][4] = {};

  #pragma unroll 1
  for (int kk = 0; kk < 4; ++kk) {
    const int k0 = kc * 256 + kk * 64;
    #pragma unroll
    for (int p = 0; p < 4; ++p) {
      const int u = p * 256 + tid;
      const int r = u >> 3, c = u & 7;
      const int4 va = *(const int4*)(spk + (size_t)(bm + r) * 2048 + k0 + c * 8);
      *(int4*)(As + r * PS + c * 8) = va;
    }
    #pragma unroll
    for (int p = 0; p < 4; ++p) {
      const int u = p * 256 + tid;
      const int n = u >> 3, c = u & 7;
      const float* wp = W2 + (size_t)n * 2048 + k0 + c * 8;
      const float4 w0 = *(const float4*)(wp);
      const float4 w1 = *(const float4*)(wp + 4);
      int4 pk;
      pk.x = (int)f2bf2(w0.x, w0.y);
      pk.y = (int)f2bf2(w0.z, w0.w);
      pk.z = (int)f2bf2(w1.x, w1.y);
      pk.w = (int)f2bf2(w1.z, w1.w);
      *(int4*)(Bs + n * PS + c * 8) = pk;
    }
    __syncthreads();

    #pragma unroll
    for (int ks = 0; ks < 2; ++ks) {
      const int kb = ks * 4 + (lane >> 4);
      const int fe = lane & 15;
      short8 a8[4], b8[4];
      #pragma unroll
      for (int tm = 0; tm < 4; ++tm)
        a8[tm] = *(const short8*)(As + (wm + tm * 16 + fe) * PS + kb * 8);
      #pragma unroll
      for (int tn = 0; tn < 4; ++tn)
        b8[tn] = *(const short8*)(Bs + (wn + tn * 16 + fe) * PS + kb * 8);
      #pragma unroll
      for (int tm = 0; tm < 4; ++tm)
        #pragma unroll
        for (int tn = 0; tn < 4; ++tn)
          acc[tm][tn] = __builtin_amdgcn_mfma_f32_16x16x32_bf16(
              a8[tm], b8[tn], acc[tm][tn], 0, 0, 0);
    }
    __syncthreads();
  }

  const int fe = lane & 15;
  const int fr = (lane >> 4) * 4;
  #pragma unroll
  for (int tm = 0; tm < 4; ++tm)
    #pragma unroll
    for (int tn = 0; tn < 4; ++tn)
      #pragma unroll
      for (int r = 0; r < 4; ++r) {
        const int row = bm + wm + tm * 16 + fr + r;
        const int col = wn + tn * 16 + fe;
        part[((size_t)kc * 4096 + row) * 128 + col] = acc[tm][tn][r];
      }
}

// ---------------------------------------------------------------------------
// Kernel 3 (R0 proven): out[m][n] = sum_kc part[kc][m][n] + b2[n]
// ---------------------------------------------------------------------------
__global__ __launch_bounds__(256) void snn_k3(
    const float* __restrict__ part, const float* __restrict__ b2,
    float* __restrict__ out)
{
  const int idx = blockIdx.x * 256 + threadIdx.x;
  const int m = idx >> 5;
  const int c = (idx & 31) << 2;
  float s0 = 0.f, s1 = 0.f, s2 = 0.f, s3 = 0.f;
  #pragma unroll
  for (int kc = 0; kc < 8; ++kc) {
    const float4 p = *(const float4*)(part + ((size_t)kc * 4096 + m) * 128 + c);
    s0 += p.x; s1 += p.y; s2 += p.z; s3 += p.w;
  }
  float4 o;
  o.x = s0 + b2[c + 0];
  o.y = s1 + b2[c + 1];
  o.z = s2 + b2[c + 2];
  o.w = s3 + b2[c + 3];
  *(float4*)(out + (size_t)m * 128 + c) = o;
}

extern "C" void kernel_launch(void* const* d_in, const int* in_sizes, int n_in,
                              void* d_out, int out_size, void* d_ws, size_t ws_size,
                              hipStream_t stream) {
  const float* X    = (const float*)d_in[0];  // [4096,256]
  const float* W1   = (const float*)d_in[1];  // [2048,256]
  const float* b1   = (const float*)d_in[2];  // [2048]
  const float* W2   = (const float*)d_in[3];  // [128,2048]
  const float* b2   = (const float*)d_in[4];  // [128]
  const float* beta = (const float*)d_in[5];  // scalar
  float* out = (float*)d_out;                 // [4096,128] fp32

  uint16_t* spk = (uint16_t*)d_ws;                                 // 16 MiB
  float* part   = (float*)((char*)d_ws + (size_t)4096 * 2048 * 2); // 16 MiB
  // cur1 half [4096,1024] fp32 (16 MiB) aliases 'part' (dead until k2):
  float* cur1h = part;

  // half 0: hidden cols 0..1023
  snn_gemm1<<<dim3(16, 32), 256, 0, stream>>>(X, W1, b1, cur1h);
  snn_rec<<<2048, 256, 0, stream>>>(cur1h, beta, spk, 0);
  // half 1: hidden cols 1024..2047
  snn_gemm1<<<dim3(16, 32), 256, 0, stream>>>(
      X, W1 + (size_t)1024 * 256, b1 + 1024, cur1h);
  snn_rec<<<2048, 256, 0, stream>>>(cur1h, beta, spk, 1024);

  snn_k2<<<dim3(32, 8), 256, 0, stream>>>(spk, W2, part);
  snn_k3<<<512, 256, 0, stream>>>(part, b2, out);
}